// Round 1
// baseline (318.822 us; speedup 1.0000x reference)
//
#include <hip/hip_runtime.h>

#define BB 4
#define NN 16384
#define SS 4096
#define CC 256
#define QB 128      // queries per block
#define CHUNK 1024  // k points staged per LDS chunk
#define NCHUNK (SS / CHUNK)
#define RQ 4        // queries per thread (register-tiled)
#define TILE_LD 260 // padded leading dim for out-transpose tile

// LDS region X (reused across phases): max(kpts 16KB, merge lists 24KB, tile 66.56KB)
#define SMEM_BYTES (64 * TILE_LD * 4)

__global__ __launch_bounds__(256, 2) void puattn_kernel(
    const float* __restrict__ qg, const float* __restrict__ kg,
    const float* __restrict__ vg, float* __restrict__ outg) {
#pragma clang fp contract(off)
  __shared__ __align__(16) char smem_raw[SMEM_BYTES];
  __shared__ float sw[QB][3];
  __shared__ int si[QB][3];

  float4* kpts = (float4*)smem_raw;          // [CHUNK] phase 1a
  float* md = (float*)smem_raw;              // [8][32][4][3] phase 1b
  int* mi = (int*)(smem_raw + 12288);        // [8][32][4][3] phase 1b
  float* tile = (float*)smem_raw;            // [64][TILE_LD] phase 2

  const int tid = threadIdx.x;
  const int blk = blockIdx.x;
  const int b = blk >> 7;           // blk / 128
  const int n0 = (blk & 127) << 7;  // 128 queries per block

  const int qlane = tid & 31;  // 32 query-lanes
  const int g = tid >> 5;      // 8 s-groups

  // ---- load my RQ queries ----
  float qx[RQ], qy[RQ], qz[RQ], qq[RQ];
  float d0[RQ], d1[RQ], d2[RQ];
  int i0[RQ], i1[RQ], i2[RQ];
#pragma unroll
  for (int j = 0; j < RQ; ++j) {
    int n = n0 + qlane + 32 * j;
    const float* qp = qg + ((long)b * NN + n) * 3;
    qx[j] = qp[0]; qy[j] = qp[1]; qz[j] = qp[2];
    qq[j] = (qx[j] * qx[j] + qy[j] * qy[j]) + qz[j] * qz[j];  // matches np sum order
    d0[j] = 3.4e38f; d1[j] = 3.4e38f; d2[j] = 3.4e38f;
    i0[j] = 0; i1[j] = 0; i2[j] = 0;
  }

  const float* kb = kg + (long)b * SS * 3;

  // ---- phase 1: chunked brute-force top-3 scan ----
  for (int c = 0; c < NCHUNK; ++c) {
    __syncthreads();  // protect kpts from previous chunk's readers
    {
      // stage 1024 points: each thread loads 4 points (3 float4 = 12 floats), packs {x,y,z,kk}
      const float4* src = (const float4*)(kb + (long)c * CHUNK * 3) + tid * 3;
      float4 f0 = src[0], f1 = src[1], f2 = src[2];
      float px[4] = {f0.x, f0.w, f1.z, f2.y};
      float py[4] = {f0.y, f1.x, f1.w, f2.z};
      float pz[4] = {f0.z, f1.y, f2.x, f2.w};
#pragma unroll
      for (int m = 0; m < 4; ++m) {
        float kk = (px[m] * px[m] + py[m] * py[m]) + pz[m] * pz[m];
        kpts[tid * 4 + m] = make_float4(px[m], py[m], pz[m], kk);
      }
    }
    __syncthreads();

    const int sbase = c * CHUNK + g * 128;
#pragma unroll 4
    for (int i = 0; i < 128; ++i) {
      float4 kp = kpts[g * 128 + i];
      int s = sbase + i;
#pragma unroll
      for (int j = 0; j < RQ; ++j) {
        // exact replication of np: d = qq - 2*dot + kk, left-to-right, no contraction.
        // (qq - 2*dot) via fma is bit-identical since 2*dot is exact.
        float dot = (qx[j] * kp.x + qy[j] * kp.y) + qz[j] * kp.z;
        float d = __builtin_fmaf(dot, -2.0f, qq[j]) + kp.w;
        bool c2 = d < d2[j];
        bool c1 = d < d1[j];
        bool c0 = d < d0[j];
        // values via min/max (tie-safe: equal values identical either way)
        float nd2 = fminf(fmaxf(d, d1[j]), d2[j]);
        float nd1 = fminf(fmaxf(d, d0[j]), d1[j]);
        float nd0 = fminf(d, d0[j]);
        // indices via strict-< selects (ascending s => earlier index wins ties, matches top_k)
        i2[j] = c1 ? i1[j] : (c2 ? s : i2[j]);
        i1[j] = c0 ? i0[j] : (c1 ? s : i1[j]);
        i0[j] = c0 ? s : i0[j];
        d2[j] = nd2; d1[j] = nd1; d0[j] = nd0;
      }
    }
  }

  // ---- phase 1b: write per-thread lists, merge 8 groups per query ----
  __syncthreads();  // last chunk's kpts reads done; md/mi alias kpts
#pragma unroll
  for (int j = 0; j < RQ; ++j) {
    int base = (((g * 32) + qlane) * 4 + j) * 3;
    md[base + 0] = d0[j]; md[base + 1] = d1[j]; md[base + 2] = d2[j];
    mi[base + 0] = i0[j]; mi[base + 1] = i1[j]; mi[base + 2] = i2[j];
  }
  __syncthreads();

  if (tid < QB) {
    const int qi = tid;
    const int ql = qi & 31, jj = qi >> 5;
    float D0 = 3.4e38f, D1 = 3.4e38f, D2 = 3.4e38f;
    int I0 = -1, I1 = -1, I2 = -1;
    for (int gg = 0; gg < 8; ++gg) {
      int base = ((gg * 32 + ql) * 4 + jj) * 3;
      for (int r = 0; r < 3; ++r) {
        float d = md[base + r];
        int s = mi[base + r];
        // lexicographic (d, idx): matches jax.lax.top_k lower-index-first tie-break
        bool b2 = (d < D2) || (d == D2 && s < I2);
        if (b2) {
          bool b1 = (d < D1) || (d == D1 && s < I1);
          if (b1) {
            D2 = D1; I2 = I1;
            bool b0 = (d < D0) || (d == D0 && s < I0);
            if (b0) { D1 = D0; I1 = I0; D0 = d; I0 = s; }
            else { D1 = d; I1 = s; }
          } else { D2 = d; I2 = s; }
        }
      }
    }
    // weights exactly as ref: recip = 1/(d+1e-8) on ascending-sorted dists
    float r0 = 1.0f / (D0 + 1e-8f);
    float r1 = 1.0f / (D1 + 1e-8f);
    float r2 = 1.0f / (D2 + 1e-8f);
    float rs = (r0 + r1) + r2;
    sw[qi][0] = r0 / rs; sw[qi][1] = r1 / rs; sw[qi][2] = r2 / rs;
    si[qi][0] = I0; si[qi][1] = I1; si[qi][2] = I2;
  }
  __syncthreads();

  // ---- phase 2: gather v rows, weighted sum, transpose via LDS, coalesced write ----
  const int wv = tid >> 6;    // wave id 0..3
  const int lane = tid & 63;  // lane = channel block (4 channels)
  const float* vb = vg + (long)b * SS * CC;

  for (int st = 0; st < 2; ++st) {
    const int qbase = st * 64;
    for (int i = 0; i < 16; ++i) {
      int qs = wv * 16 + i;  // 0..63 within sub-tile
      int qi = qbase + qs;
      float w0 = sw[qi][0], w1 = sw[qi][1], w2 = sw[qi][2];
      const float4* r0p = (const float4*)(vb + (long)si[qi][0] * CC);
      const float4* r1p = (const float4*)(vb + (long)si[qi][1] * CC);
      const float4* r2p = (const float4*)(vb + (long)si[qi][2] * CC);
      float4 a0 = r0p[lane], a1 = r1p[lane], a2 = r2p[lane];
      float4 acc;
      acc.x = (w0 * a0.x + w1 * a1.x) + w2 * a2.x;
      acc.y = (w0 * a0.y + w1 * a1.y) + w2 * a2.y;
      acc.z = (w0 * a0.z + w1 * a1.z) + w2 * a2.z;
      acc.w = (w0 * a0.w + w1 * a1.w) + w2 * a2.w;
      *(float4*)&tile[qs * TILE_LD + lane * 4] = acc;
    }
    __syncthreads();
    {
      int qs2 = tid & 63;       // lane-fastest over n for coalescing
      int cb = tid >> 6;        // 0..3
      long nout = (long)n0 + qbase + qs2;
      for (int it = 0; it < 64; ++it) {
        int cch = cb + it * 4;
        outg[((long)(b * CC + cch)) * NN + nout] = tile[qs2 * TILE_LD + cch];
      }
    }
    __syncthreads();
  }
}

extern "C" void kernel_launch(void* const* d_in, const int* in_sizes, int n_in,
                              void* d_out, int out_size, void* d_ws, size_t ws_size,
                              hipStream_t stream) {
  const float* q = (const float*)d_in[0];
  const float* k = (const float*)d_in[1];
  const float* v = (const float*)d_in[2];
  float* out = (float*)d_out;
  hipLaunchKernelGGL(puattn_kernel, dim3(512), dim3(256), 0, stream, q, k, v, out);
}